// Round 7
// baseline (108.927 us; speedup 1.0000x reference)
//
#include <hip/hip_runtime.h>

#define NEGC  (-1000000000.0f)
#define NEG2C (-1.4426950408889634e9f)
#define LOG2E 1.4426950408889634f
#define LN2   0.6931471805599453f

constexpr int B_=64, M_=16, L_=128;
constexpr long OFF_FTS=0;
constexpr long OFF_FMS=OFF_FTS+(long)B_*M_*L_;
constexpr long OFF_LA =OFF_FMS+(long)B_*M_*L_;
constexpr long OFF_ELA=OFF_LA+B_;
constexpr long OFF_LB =OFF_ELA+(long)B_*M_*L_;
constexpr long OFF_ELB=OFF_LB+(long)B_*L_;
constexpr long OFF_ENT=OFF_ELB+(long)B_*L_*M_*L_;
constexpr long OFF_EE =OFF_ENT+B_;

constexpr int LDSS=132;   // staging row stride (banks 4m+l -> 2-way only)
constexpr int RSTR=33;    // tile row stride
constexpr int GSTR=536;   // per-seq tile (16*33+8); 536%32=24 -> uniform 2-way
constexpr int ET_OFF=2112;   // E staging
constexpr int TL_OFF=4224;   // tiles
constexpr int WV_T=2144;     // per-wave tile region (4 * 536)
constexpr int FR=17, FT=280, FG=560;   // fwd layout (R5/R6, proven)

template<int CTRL>
__device__ __forceinline__ float dppf(float x){
  return __int_as_float(__builtin_amdgcn_update_dpp(0,__float_as_int(x),CTRL,0xF,0xF,true));
}
__device__ __forceinline__ float red16(float x){
  x += dppf<0xB1>(x); x += dppf<0x4E>(x); x += dppf<0x141>(x); x += dppf<0x140>(x);
  return x;
}
__device__ __forceinline__ float red8(float x){
  x += dppf<0xB1>(x); x += dppf<0x4E>(x); x += dppf<0x141>(x);
  return x;
}
__device__ __forceinline__ float fexp2(float x){
#if __has_builtin(__builtin_amdgcn_exp2f)
  return __builtin_amdgcn_exp2f(x);
#else
  return __builtin_exp2f(x);
#endif
}
__device__ __forceinline__ float flog2(float x){
#if __has_builtin(__builtin_amdgcn_logf)
  return __builtin_amdgcn_logf(x);
#else
  return __builtin_log2f(x);
#endif
}
__device__ __forceinline__ float frcp(float x){
#if __has_builtin(__builtin_amdgcn_rcpf)
  return __builtin_amdgcn_rcpf(x);
#else
  return 1.0f/x;
#endif
}

// grid: blk 0..3 fwd+entropy; blk 4..1027 backward
__global__ __launch_bounds__(128) void tok_main(
    const float* __restrict__ fwd_ts, const float* __restrict__ fwd_ms,
    const float* __restrict__ bwd_ts, const float* __restrict__ bwd_ms,
    const int* __restrict__ lengths, float* __restrict__ out)
{
  __shared__ float smem[8960];
  const int tid  = threadIdx.x;
  const int blk  = blockIdx.x;
  const int lane = tid & 63;
  const int wv   = tid >> 6;
  const int m    = lane & 15;
  const int g    = lane >> 4;

  if (blk >= 4) {
    // ================= backward (linear scan, fully deferred epilogue) =================
    const int bk  = blk - 4;
    const int b   = bk >> 4;
    const int sub = bk & 15;
    const int j   = sub + 16*(wv*4 + g);

    if (tid < 16) {          // folded pass-through copies
      const float4* s0 = (const float4*)fwd_ts;
      const float4* s1 = (const float4*)fwd_ms;
      int idx = bk*16 + tid;
      float4 v = (idx < 8192) ? s0[idx] : s1[idx - 8192];
      ((float4*)out)[idx] = v;
    }

    // stage t (natural) and E = e^t
    const float4* gts = (const float4*)(bwd_ts + (long)b*2048);
    #pragma unroll
    for (int it=0; it<4; ++it){
      int t4 = it*128 + tid;
      float4 a = gts[t4];
      int mr = t4 >> 5, l4 = (t4 & 31) << 2;
      float* dt = smem + mr*LDSS + l4;
      float* de = smem + ET_OFF + mr*LDSS + l4;
      dt[0]=a.x; dt[1]=a.y; dt[2]=a.z; dt[3]=a.w;
      de[0]=fexp2(a.x*LOG2E); de[1]=fexp2(a.y*LOG2E);
      de[2]=fexp2(a.z*LOG2E); de[3]=fexp2(a.w*LOG2E);
    }
    __syncthreads();

    const int len = lengths[b];
    const int lenm1 = len - 1;
    const int thr  = 127 - j + m;             // em = (l >= thr)
    const int thrp = (m==0) ? 0 : thr;        // w used iff (l>=thrp)&&(l<len)
    const float* rowt = smem + m*LDSS;
    const float* rowe = smem + ET_OFF + m*LDSS;
    float* wbase = smem + TL_OFF + wv*WV_T;
    float* buf = wbase + g*GSTR + m*RSTR;
    const int fm = lane >> 3;
    const int fk = (lane & 7) << 2;

    float W = 1.0f, keepT = 1.0f;
    int refI = 0, keepR = 0;

    float Ev[32];
    {
      const float4* ep = (const float4*)rowe;
      #pragma unroll
      for (int r=0; r<8; ++r){
        float4 v = ep[r];
        Ev[4*r]=v.x; Ev[4*r+1]=v.y; Ev[4*r+2]=v.z; Ev[4*r+3]=v.w;
      }
    }

    for (int c=0; c<4; ++c){
      const int lb = c << 5;
      const int thrC  = thr  - lb;
      const int thrpC = thrp - lb;
      const int lenC  = len  - lb;
      const int lm1C  = lenm1 - lb;
      const int refEntry = refI;
      int refMid = refI;
      float Wh[32];

      // ---- scan: chain = cndmask, mul, cndmask, red16, cndmask ----
      #pragma unroll
      for (int t=0; t<32; ++t){
        const bool em = (t >= thrC);
        const bool uw = (t >= thrpC) && (t < lenC);
        float e = em ? Ev[t] : 1.0f;
        float x = W * e;
        float s = uw ? x : 0.0f;
        float tot = red16(s);
        keepT = (t == lm1C) ? tot : keepT;
        keepR = (t == lm1C) ? refI : keepR;
        Wh[t] = W;                          // pre-update value (= w at this step)
        float sh = dppf<0x111>(W);
        W = (m==0) ? tot : sh;
        if (t==15 || t==31){                // cheap renorm: exponent extract + ldexp
          int ef = (int)((__float_as_uint(tot) >> 23) & 255) - 127;
          W = ldexpf(W, -ef);
          refI += ef;
          if (t==15) refMid = refI;
        }
      }

      // ---- bulk loads (pipelined, off-chain) ----
      float Tn[32], Evn[32];
      {
        const float4* tp = (const float4*)(rowt + lb);
        #pragma unroll
        for (int r=0; r<8; ++r){
          float4 v = tp[r];
          Tn[4*r]=v.x; Tn[4*r+1]=v.y; Tn[4*r+2]=v.z; Tn[4*r+3]=v.w;
        }
        if (c < 3){
          const float4* ep = (const float4*)(rowe + lb + 32);
          #pragma unroll
          for (int r=0; r<8; ++r){
            float4 v = ep[r];
            Evn[4*r]=v.x; Evn[4*r+1]=v.y; Evn[4*r+2]=v.z; Evn[4*r+3]=v.w;
          }
        }
      }

      // ---- epilogue: 32 independent logs + LDS tile writes ----
      const float refF0 = (float)refEntry, refF1 = (float)refMid;
      #pragma unroll
      for (int t=0; t<32; ++t){
        const bool em = (t >= thrC);
        const bool uw = (t >= thrpC) && (t < lenC);
        float lg = flog2(fmaxf(Wh[t], 1e-30f));
        float wn = (lg + (t < 16 ? refF0 : refF1)) * LN2;   // natural-log w
        float cc = (em ? Tn[t] : 0.0f) + (uw ? wn : NEGC);
        buf[t] = em ? cc : NEGC;
      }

      // ---- flush: full 128-B sectors (same-wave LDS ordering) ----
      #pragma unroll
      for (int g2=0; g2<4; ++g2){
        const int j2 = sub + 16*(wv*4 + g2);
        float* db = out + OFF_ELB + ((long)(b*128 + j2) << 11) + lb;
        const float* s1p = wbase + g2*GSTR + fm*RSTR + fk;
        *(float4*)(db + fm*128 + fk) = make_float4(s1p[0], s1p[1], s1p[2], s1p[3]);
        const float* s2p = wbase + g2*GSTR + (fm+8)*RSTR + fk;
        *(float4*)(db + (fm+8)*128 + fk) = make_float4(s2p[0], s2p[1], s2p[2], s2p[3]);
      }

      if (c < 3){
        #pragma unroll
        for (int t=0; t<32; ++t) Ev[t] = Evn[t];
      }
    }
    if (m == 0)
      out[OFF_LB + (long)b*128 + j] =
          (flog2(fmaxf(keepT, 1e-30f)) + (float)keepR) * LN2;

  } else {
    // ================= forward + entropy (R6 structure, proven) =================
    const int p  = lane & 7;
    const int gw = lane >> 3;
    const int b = blk*16 + wv*8 + gw;
    const int len = lengths[b];
    const int lenm1 = len - 1;
    const float* ftA = fwd_ts + ((long)b*16 + p)*128;
    const float* ftB = fwd_ts + ((long)b*16 + p + 8)*128;
    float w2A=0.f, w2B=0.f, whA=0.f, whB=0.f, stab=0.f, la_keep=0.f, h_keep=0.f;
    float* base = smem + (wv*8 + gw)*FG;
    float* eA  = base + p*FR;
    float* eB  = base + (p+8)*FR;
    float* hA  = base + FT + p*FR;
    float* hB  = base + FT + (p+8)*FR;
    const int fm2 = lane >> 2;
    const int fk2 = (lane & 3) << 2;

    float4 a4 = *(const float4*)(ftA);
    float4 b4 = *(const float4*)(ftB);
    for (int j0 = 0; j0 < 128; j0 += 4){
      float4 a4n, b4n;
      if (j0 < 124){ a4n = *(const float4*)(ftA + j0 + 4);
                     b4n = *(const float4*)(ftB + j0 + 4); }
      float tA[4]={a4.x,a4.y,a4.z,a4.w}, tB[4]={b4.x,b4.y,b4.z,b4.w};
      #pragma unroll
      for (int kk=0; kk<4; ++kk){
        const int jj = j0 + kk;
        const bool vA = (p <= jj) && (jj < len);
        const bool vB = (p+8 <= jj) && (jj < len);
        float cA = tA[kk]*LOG2E + (vA ? w2A : NEG2C);
        float cB = tB[kk]*LOG2E + (vB ? w2B : NEG2C);
        float dA = cA - stab, dB = cB - stab;
        float sA = fexp2(dA), sB = fexp2(dB);
        float tot = red8(sA + sB);
        float lg = flog2(tot);
        float la = stab + lg;
        float rt = frcp(tot);
        float coA = vA ? (sA*rt) * (whA + (lg - dA)*LN2) : 0.f;
        float coB = vB ? (sB*rt) * (whB + (lg - dB)*LN2) : 0.f;
        float h = red8(coA + coB);
        eA[jj & 15] = cA*LN2;
        eB[jj & 15] = cB*LN2;
        hA[jj & 15] = coA;
        hB[jj & 15] = coB;
        if (jj == lenm1){ la_keep = la; h_keep = h; }
        float mirW = dppf<0x141>(w2A);
        float mirH = dppf<0x141>(whA);
        float sWA = dppf<0x111>(w2A), sWB = dppf<0x111>(w2B);
        float sHA = dppf<0x111>(whA), sHB = dppf<0x111>(whB);
        w2A = (p==0) ? la   : sWA;
        w2B = (p==0) ? mirW : sWB;
        whA = (p==0) ? h    : sHA;
        whB = (p==0) ? mirH : sHB;
        stab = la;
      }
      if ((j0 & 15) == 12){
        const int jb = j0 - 12;
        #pragma unroll
        for (int g2=0; g2<8; ++g2){
          const int b2 = blk*16 + wv*8 + g2;
          const float* sb = smem + (wv*8 + g2)*FG;
          const float* sp = sb + fm2*FR + fk2;
          *(float4*)(out + OFF_ELA + ((long)b2*16 + fm2)*128 + jb + fk2) =
              make_float4(sp[0], sp[1], sp[2], sp[3]);
          const float* sp2 = sb + FT + fm2*FR + fk2;
          *(float4*)(out + OFF_EE + ((long)b2*16 + fm2)*128 + jb + fk2) =
              make_float4(sp2[0], sp2[1], sp2[2], sp2[3]);
        }
      }
      a4 = a4n; b4 = b4n;
    }
    if (p == 0){
      out[OFF_LA + b] = la_keep * LN2;
      out[OFF_ENT + b] = h_keep;
    }
  }
}

extern "C" void kernel_launch(void* const* d_in, const int* in_sizes, int n_in,
                              void* d_out, int out_size, void* d_ws, size_t ws_size,
                              hipStream_t stream) {
  const float* fts = (const float*)d_in[0];
  const float* fms = (const float*)d_in[1];
  const float* bts = (const float*)d_in[2];
  const float* bms = (const float*)d_in[3];
  const int*   len = (const int*)d_in[4];
  float* out = (float*)d_out;
  hipLaunchKernelGGL(tok_main, dim3(1028), dim3(128), 0, stream,
                     fts, fms, bts, bms, len, out);
}

// Round 8
// 101.724 us; speedup vs baseline: 1.0708x; 1.0708x over previous
//
#include <hip/hip_runtime.h>

#define NEGC  (-1000000000.0f)
#define NEG2C (-1.4426950408889634e9f)
#define LOG2E 1.4426950408889634f
#define LN2   0.6931471805599453f

constexpr int B_=64, M_=16, L_=128;
constexpr long OFF_FTS=0;
constexpr long OFF_FMS=OFF_FTS+(long)B_*M_*L_;
constexpr long OFF_LA =OFF_FMS+(long)B_*M_*L_;
constexpr long OFF_ELA=OFF_LA+B_;
constexpr long OFF_LB =OFF_ELA+(long)B_*M_*L_;
constexpr long OFF_ELB=OFF_LB+(long)B_*L_;
constexpr long OFF_ENT=OFF_ELB+(long)B_*L_*M_*L_;
constexpr long OFF_EE =OFF_ENT+B_;

constexpr int RSTR=33;            // bwd tile row stride (16 rows x 32 cols)
constexpr int GSTR=536;           // per-seq bwd tile (16*33+8)
constexpr int FR=17, FT=280, FG=560;  // fwd tiles (proven layout)

template<int CTRL>
__device__ __forceinline__ float dppf(float x){
  return __int_as_float(__builtin_amdgcn_update_dpp(0,__float_as_int(x),CTRL,0xF,0xF,true));
}
__device__ __forceinline__ float red16(float x){
  x += dppf<0xB1>(x); x += dppf<0x4E>(x); x += dppf<0x141>(x); x += dppf<0x140>(x);
  return x;
}
__device__ __forceinline__ float fexp2(float x){
#if __has_builtin(__builtin_amdgcn_exp2f)
  return __builtin_amdgcn_exp2f(x);
#else
  return __builtin_exp2f(x);
#endif
}
__device__ __forceinline__ float flog2(float x){
#if __has_builtin(__builtin_amdgcn_logf)
  return __builtin_amdgcn_logf(x);
#else
  return __builtin_log2f(x);
#endif
}
__device__ __forceinline__ float frcp(float x){
#if __has_builtin(__builtin_amdgcn_rcpf)
  return __builtin_amdgcn_rcpf(x);
#else
  return 1.0f/x;
#endif
}

// 64-thread blocks, 1 wave each, NO barriers.
// blk 0..15: fwd+entropy (4 seqs). blk 16..47: copies. blk 48..2095: backward (4 seqs).
__global__ __launch_bounds__(64, 4) void tok_main(
    const float* __restrict__ fwd_ts, const float* __restrict__ fwd_ms,
    const float* __restrict__ bwd_ts, const float* __restrict__ bwd_ms,
    const int* __restrict__ lengths, float* __restrict__ out)
{
  __shared__ float smem[2240];     // max(bwd 4*536, fwd 4*560) floats
  const int tid  = threadIdx.x;    // == lane (64-thread blocks)
  const int blk  = blockIdx.x;
  const int m    = tid & 15;
  const int g    = tid >> 4;       // group 0..3

  if (blk >= 48) {
    // ================= backward: 4 seqs, linear scan, G-shift for logs =================
    const int bk  = blk - 48;      // 0..2047
    const int b   = bk >> 5;
    const int sub = bk & 31;
    const int j   = sub*4 + g;     // 4 consecutive j's per block

    const int len   = lengths[b];
    const int lm1   = len - 1;
    const int thr   = 127 - j + m;            // em = (l >= thr)
    const int thrp  = (m==0) ? 0 : thr;       // w consumed iff (l>=thrp)&&(l<len)
    const float* tg = bwd_ts + (long)b*2048 + m*128;
    float* buf = smem + g*GSTR + m*RSTR;
    const int fm = tid >> 3;                  // flush row 0..7
    const int fk = (tid & 7) << 2;            // flush col*4

    float W = 1.0f;      // linear scan state (renormalized)
    float G = 0.0f;      // ln(w) shift register: pre-update G = la(l-1-m), abs value
    float refN = 0.0f;   // natural-log renorm accumulator
    float keepT = 1.0f, keepR = 0.0f;

    for (int c = 0; c < 4; ++c){
      const int lb = c << 5;
      const int thrC  = thr  - lb;
      const int thrpC = thrp - lb;
      const int lenC  = len  - lb;
      const int lm1C  = lm1  - lb;

      float T[32];
      {
        const float4* tp = (const float4*)(tg + lb);
        #pragma unroll
        for (int r=0; r<8; ++r){
          float4 v = tp[r];
          T[4*r]=v.x; T[4*r+1]=v.y; T[4*r+2]=v.z; T[4*r+3]=v.w;
        }
      }

      #pragma unroll
      for (int t=0; t<32; ++t){
        const bool em = (t >= thrC);
        const bool uw = (t >= thrpC) && (t < lenC);
        // chain: cndmask, mul, cndmask, 4x dpp-add, cndmask
        float e  = em ? fexp2(T[t]*LOG2E) : 1.0f;   // exp off-chain (hoistable)
        float x  = W * e;
        float s  = uw ? x : 0.0f;
        float tot = red16(s);
        // elb (all off-chain): pre-update G == la(l-1-m) for every lane incl. m==0
        float val = em ? (T[t] + (uw ? G : NEGC)) : NEGC;
        buf[t] = val;
        keepT = (t == lm1C) ? tot : keepT;
        keepR = (t == lm1C) ? refN : keepR;
        float lg = flog2(tot)*LN2 + refN;           // feeds NEXT step's G only
        float Gs = dppf<0x111>(G);
        G = (m==0) ? lg : Gs;
        float Ws = dppf<0x111>(W);
        W = (m==0) ? tot : Ws;
        if (t==15 || t==31){                        // cheap renorm, off transcendentals
          int ef = (int)((__float_as_uint(tot) >> 23) & 255) - 127;
          W = ldexpf(W, -ef);
          refN += (float)ef * LN2;
        }
      }

      // flush 4 tiles: full 128-B sectors (same-wave LDS ordering, no barrier)
      #pragma unroll
      for (int g2=0; g2<4; ++g2){
        const int j2 = sub*4 + g2;
        float* db = out + OFF_ELB + ((long)(b*128 + j2) << 11) + lb;
        const float* s1p = smem + g2*GSTR + fm*RSTR + fk;
        *(float4*)(db + fm*128 + fk) = make_float4(s1p[0], s1p[1], s1p[2], s1p[3]);
        const float* s2p = smem + g2*GSTR + (fm+8)*RSTR + fk;
        *(float4*)(db + (fm+8)*128 + fk) = make_float4(s2p[0], s2p[1], s2p[2], s2p[3]);
      }
    }
    if (m == 0)
      out[OFF_LB + (long)b*128 + j] = flog2(fmaxf(keepT, 1e-30f))*LN2 + keepR;

  } else if (blk < 16) {
    // ================= forward + entropy: 4 seqs, 16-lane groups =================
    const int b = blk*4 + g;
    const int len = lengths[b];
    const int lm1 = len - 1;
    const float* fts = fwd_ts + ((long)b*16 + m)*128;
    float w2=0.f, wh=0.f, stab=0.f, la_keep=0.f, h_keep=0.f;
    float* eT = smem + g*FG + m*FR;
    float* hT = smem + g*FG + FT + m*FR;
    const int fm2 = tid >> 2;        // 0..15
    const int fk2 = (tid & 3) << 2;  // 0..12

    for (int j0 = 0; j0 < 128; j0 += 4){
      float4 tv = *(const float4*)(fts + j0);
      float ta[4] = {tv.x, tv.y, tv.z, tv.w};
      #pragma unroll
      for (int kk=0; kk<4; ++kk){
        const int jj = j0 + kk;
        const bool valid = (m <= jj) && (jj < len);
        float c2 = ta[kk]*LOG2E + (valid ? w2 : NEG2C);
        float d  = c2 - stab;
        float s  = fexp2(d);
        float tot = red16(s);
        float lg = flog2(tot);
        float la = stab + lg;
        float q  = s * frcp(tot);
        float contrib = valid ? q * (wh + (lg - d)*LN2) : 0.f;
        float h = red16(contrib);
        eT[jj & 15] = c2*LN2;
        hT[jj & 15] = contrib;
        if (jj == lm1){ la_keep = la; h_keep = h; }
        float sW = dppf<0x111>(w2);
        float sH = dppf<0x111>(wh);
        w2 = (m==0) ? la : sW;
        wh = (m==0) ? h  : sH;
        stab = la;
      }
      if ((j0 & 15) == 12){
        const int jb = j0 - 12;
        #pragma unroll
        for (int g2=0; g2<4; ++g2){
          const int b2 = blk*4 + g2;
          const float* sb = smem + g2*FG;
          const float* sp = sb + fm2*FR + fk2;
          *(float4*)(out + OFF_ELA + ((long)b2*16 + fm2)*128 + jb + fk2) =
              make_float4(sp[0], sp[1], sp[2], sp[3]);
          const float* sp2 = sb + FT + fm2*FR + fk2;
          *(float4*)(out + OFF_EE + ((long)b2*16 + fm2)*128 + jb + fk2) =
              make_float4(sp2[0], sp2[1], sp2[2], sp2[3]);
        }
      }
    }
    if (m == 0){
      out[OFF_LA + b]  = la_keep * LN2;
      out[OFF_ENT + b] = h_keep;
    }

  } else {
    // ================= pass-through copies (blk 16..47) =================
    const int cbk = blk - 16;
    const float4* s0 = (const float4*)fwd_ts;
    const float4* s1 = (const float4*)fwd_ms;
    float4* d = (float4*)out;
    #pragma unroll
    for (int it=0; it<8; ++it){
      int idx = it*2048 + cbk*64 + tid;   // 0..16383
      float4 v = (idx < 8192) ? s0[idx] : s1[idx - 8192];
      d[idx] = v;
    }
  }
}

extern "C" void kernel_launch(void* const* d_in, const int* in_sizes, int n_in,
                              void* d_out, int out_size, void* d_ws, size_t ws_size,
                              hipStream_t stream) {
  const float* fts = (const float*)d_in[0];
  const float* fms = (const float*)d_in[1];
  const float* bts = (const float*)d_in[2];
  const float* bms = (const float*)d_in[3];
  const int*   len = (const int*)d_in[4];
  float* out = (float*)d_out;
  hipLaunchKernelGGL(tok_main, dim3(2096), dim3(64), 0, stream,
                     fts, fms, bts, bms, len, out);
}